// Round 7
// baseline (621.865 us; speedup 1.0000x reference)
//
#include <hip/hip_runtime.h>
#include <cstdint>
#include <cstddef>

// Round 7 = round 6 kernel, resubmitted (round 6 died in GPU-acquisition
// timeout; the gemm8p schedule has never yet run on hardware).
// gemm8p: big-3 GEMMs on a liveness-proven 3-buffer 2-phase/BK=64 schedule
// (16 MFMA per phase, counted vmcnt(6), never 0 in loop).

// ---------------------------------------------------------------- types
typedef __bf16 bf16x8 __attribute__((ext_vector_type(8)));
typedef float  f32x4  __attribute__((ext_vector_type(4)));

#define LDS_AS __attribute__((address_space(3)))
#define GLB_AS __attribute__((address_space(1)))

static __device__ __forceinline__ unsigned short f2bf(float f) {
    unsigned int u = __float_as_uint(f);
    u += 0x7fffu + ((u >> 16) & 1u);   // RNE; inputs are finite/normal
    return (unsigned short)(u >> 16);
}

// ---------------------------------------------------------------- fp32 -> bf16
__global__ __launch_bounds__(256) void cvt_f32_bf16(const float* __restrict__ in,
                                                    unsigned short* __restrict__ out, int n4) {
    int stride = gridDim.x * blockDim.x;
    for (int i = blockIdx.x * blockDim.x + threadIdx.x; i < n4; i += stride) {
        float4 f = reinterpret_cast<const float4*>(in)[i];
        ushort4 u;
        u.x = f2bf(f.x); u.y = f2bf(f.y); u.z = f2bf(f.z); u.w = f2bf(f.w);
        reinterpret_cast<ushort4*>(out)[i] = u;
    }
}

// ---------------------------------------------------------------- PE frequency table
__global__ void divtab_kernel(float* __restrict__ dtab) {
    int i = threadIdx.x;                       // 256 threads
    dtab[i] = expf((float)(2 * i) * (-9.210340371976184f / 512.0f));
}

// ================================================================ 128x256 BK=64 GEMM
// C = A @ B^T (relu+bias -> bf16).  512 threads = 8 waves (2M x 4N), per-wave 64x64.
// 3 LDS buffers x (A 16KB + B 32KB) = 144 KiB. Tile t computes buf t%3; ALL 6 loads
// of tile t+2 issued at t.P0 into buf (t+2)%3 (== buf (t-1)%3, fully read by then).
// Gate: vmcnt(6) at t.P1 drains tile t+1, leaves t+2's 6 loads in flight (~2 tiles
// of latency cover). Never drains to 0 in the main loop.
// k-slot XOR swizzle: LDS(row r, slot j) holds global k-slot j^(r&7); read applies
// the same involution -> ds_read_b128 ~conflict-free, global_load_lds dest linear.
template<int ID>
__global__ __launch_bounds__(512, 2) void gemm8p(
    const unsigned short* __restrict__ A, int lda,
    const unsigned short* __restrict__ B, int ldb,
    int M, int N, int K,
    const float* __restrict__ bias,
    unsigned short* __restrict__ Cb, int ldc)
{
    constexpr int ABYTES = 128 * 64 * 2;          // 16384
    constexpr int SLOT   = ABYTES + 256 * 64 * 2; // 49152
    __shared__ __align__(16) unsigned char lds[3 * SLOT];   // 144 KiB

    const int nbn = N >> 8;
    int wg = blockIdx.x;
    { int q = gridDim.x >> 3; wg = (wg & 7) * q + (wg >> 3); }  // grids %8==0
    const int bm = wg / nbn, bn = wg % nbn;

    const int t = threadIdx.x;
    const int lane = t & 63, wid = t >> 6;
    const int wr = wid >> 2, wc = wid & 3;        // wave grid 2M x 4N
    const int l15 = lane & 15, l4 = lane >> 4;

    // ---- staging (per thread 16B): row-in-64 = t>>3, LDS slot j = t&7,
    //      global k-slot = j ^ (row&7)  (row&7 == srow&7 for all 64-row groups)
    const int srow = t >> 3, sj = t & 7;
    const int skA = (sj ^ (srow & 7)) * 8;        // element offset within BK=64
    const unsigned short* gA = A + (size_t)(bm * 128 + srow) * lda + skA;
    const unsigned short* gB = B + (size_t)(bn * 256 + srow) * ldb + skA;
    const size_t a64 = (size_t)64 * lda, b64 = (size_t)64 * ldb;

    // ---- ds_read offsets: byte = row*128 + ((kk*4+l4)^(l15&7))*16
    const int ks0 = ((0 * 4 + l4) ^ (l15 & 7)) * 16;
    const int ks1 = ((1 * 4 + l4) ^ (l15 & 7)) * 16;
    const int arow = (wr * 64 + l15) * 128;              // + mi*2048
    const int brow = ABYTES + (wc * 64 + l15) * 128;     // + ni*2048

    f32x4 acc[4][4];
    const f32x4 z = {0.f, 0.f, 0.f, 0.f};
#pragma unroll
    for (int i = 0; i < 4; i++)
#pragma unroll
        for (int j = 0; j < 4; j++) acc[i][j] = z;

    const int nt = K >> 6;

#define STAGE(kt_) do { unsigned char* d_ = &lds[((kt_) % 3) * SLOT];                       \
        const unsigned short* a_ = gA + (size_t)(kt_) * 64;                                 \
        const unsigned short* b_ = gB + (size_t)(kt_) * 64;                                 \
        __builtin_amdgcn_global_load_lds((const GLB_AS void*)a_,         (LDS_AS void*)(d_ + t * 16),                 16, 0, 0); \
        __builtin_amdgcn_global_load_lds((const GLB_AS void*)(a_ + a64), (LDS_AS void*)(d_ + 8192 + t * 16),          16, 0, 0); \
        __builtin_amdgcn_global_load_lds((const GLB_AS void*)b_,         (LDS_AS void*)(d_ + ABYTES + t * 16),        16, 0, 0); \
        __builtin_amdgcn_global_load_lds((const GLB_AS void*)(b_ + b64), (LDS_AS void*)(d_ + ABYTES + 8192 + t * 16), 16, 0, 0); \
        __builtin_amdgcn_global_load_lds((const GLB_AS void*)(b_ + 2 * b64), (LDS_AS void*)(d_ + ABYTES + 16384 + t * 16), 16, 0, 0); \
        __builtin_amdgcn_global_load_lds((const GLB_AS void*)(b_ + 3 * b64), (LDS_AS void*)(d_ + ABYTES + 24576 + t * 16), 16, 0, 0); \
    } while (0)

    // ---- prologue: tiles 0,1 staged; tile 0 landed, tile 1 (6 loads) in flight
    STAGE(0);
    STAGE(1);
    asm volatile("s_waitcnt vmcnt(6)" ::: "memory");
    __builtin_amdgcn_s_barrier();
    __builtin_amdgcn_sched_barrier(0);

    for (int kt = 0; kt < nt; ++kt) {
        const LDS_AS unsigned char* s = (const LDS_AS unsigned char*)&lds[(kt % 3) * SLOT];

        // ---------------- phase 0: ni 0-1 (12 ds_reads + stage t+2) ----------------
        bf16x8 af[4][2], bf[2][2];
#pragma unroll
        for (int mi = 0; mi < 4; ++mi) {
            af[mi][0] = *(const LDS_AS bf16x8*)(s + arow + mi * 2048 + ks0);
            af[mi][1] = *(const LDS_AS bf16x8*)(s + arow + mi * 2048 + ks1);
        }
#pragma unroll
        for (int ni = 0; ni < 2; ++ni) {
            bf[ni][0] = *(const LDS_AS bf16x8*)(s + brow + ni * 2048 + ks0);
            bf[ni][1] = *(const LDS_AS bf16x8*)(s + brow + ni * 2048 + ks1);
        }
        if (kt + 2 < nt) STAGE(kt + 2);
        __builtin_amdgcn_s_barrier();
        asm volatile("s_waitcnt lgkmcnt(0)" ::: "memory");
        __builtin_amdgcn_sched_barrier(0);
        __builtin_amdgcn_s_setprio(1);
#pragma unroll
        for (int mi = 0; mi < 4; ++mi)
#pragma unroll
            for (int ni = 0; ni < 2; ++ni) {
                acc[mi][ni] = __builtin_amdgcn_mfma_f32_16x16x32_bf16(af[mi][0], bf[ni][0], acc[mi][ni], 0, 0, 0);
                acc[mi][ni] = __builtin_amdgcn_mfma_f32_16x16x32_bf16(af[mi][1], bf[ni][1], acc[mi][ni], 0, 0, 0);
            }
        __builtin_amdgcn_s_setprio(0);
        __builtin_amdgcn_sched_barrier(0);
        __builtin_amdgcn_s_barrier();

        // ---------------- phase 1: ni 2-3 (4 ds_reads + counted vmcnt) -------------
#pragma unroll
        for (int ni = 0; ni < 2; ++ni) {
            bf[ni][0] = *(const LDS_AS bf16x8*)(s + brow + (2 + ni) * 2048 + ks0);
            bf[ni][1] = *(const LDS_AS bf16x8*)(s + brow + (2 + ni) * 2048 + ks1);
        }
        if (kt + 2 < nt) asm volatile("s_waitcnt vmcnt(6)" ::: "memory");  // drains t+1
        else             asm volatile("s_waitcnt vmcnt(0)" ::: "memory");  // tail drain
        __builtin_amdgcn_s_barrier();
        asm volatile("s_waitcnt lgkmcnt(0)" ::: "memory");
        __builtin_amdgcn_sched_barrier(0);
        __builtin_amdgcn_s_setprio(1);
#pragma unroll
        for (int mi = 0; mi < 4; ++mi)
#pragma unroll
            for (int ni = 0; ni < 2; ++ni) {
                acc[mi][2 + ni] = __builtin_amdgcn_mfma_f32_16x16x32_bf16(af[mi][0], bf[ni][0], acc[mi][2 + ni], 0, 0, 0);
                acc[mi][2 + ni] = __builtin_amdgcn_mfma_f32_16x16x32_bf16(af[mi][1], bf[ni][1], acc[mi][2 + ni], 0, 0, 0);
            }
        __builtin_amdgcn_s_setprio(0);
        __builtin_amdgcn_sched_barrier(0);
        __builtin_amdgcn_s_barrier();
    }
#undef STAGE

    // ---------------- epilogue: relu+bias -> bf16 ----------------
    const int row0 = bm * 128 + wr * 64;
    const int col0 = bn * 256 + wc * 64;
#pragma unroll
    for (int mi = 0; mi < 4; mi++) {
#pragma unroll
        for (int ni = 0; ni < 4; ni++) {
            f32x4 c = acc[mi][ni];
            const int col = col0 + ni * 16 + l15;
            const float bv = bias[col];
#pragma unroll
            for (int r = 0; r < 4; r++) {
                const int row = row0 + mi * 16 + l4 * 4 + r;
                Cb[(size_t)row * ldc + col] = f2bf(fmaxf(c[r] + bv, 0.f));
            }
        }
    }
}

// ---------------------------------------------------------------- GEMM  C = A @ B^T (m97 128x128)
// EPI: 0 = relu+bias -> bf16; 1 = bias -> bf16; 2 = bias+posenc -> bf16 AND f32; 3 = *scale -> f32
template<int EPI>
__global__ __launch_bounds__(256) void gemm_bt(
    const unsigned short* __restrict__ A, int lda,
    const unsigned short* __restrict__ B, int ldb,
    int M, int N, int K,
    const float* __restrict__ bias,
    unsigned short* __restrict__ Cb, float* __restrict__ Cf, int ldc,
    float scale, const float* __restrict__ dtab)
{
    __shared__ unsigned short ldsA[128 * 32];
    __shared__ unsigned short ldsB[128 * 32];

    const int nbn = N >> 7;
    const int bm = blockIdx.x / nbn, bn = blockIdx.x % nbn;
    const int t = threadIdx.x;
    const int lane = t & 63, wid = t >> 6;
    const int wr = wid >> 1, wc = wid & 1;
    const int l15 = lane & 15, l4 = lane >> 4;

    const unsigned short* ga0 = A + (size_t)(bm * 128 + (t >> 2)) * lda + (t & 3) * 8;
    const unsigned short* gb0 = B + (size_t)(bn * 128 + (t >> 2)) * ldb + (t & 3) * 8;
    const size_t a64 = (size_t)64 * lda, b64 = (size_t)64 * ldb;
    LDS_AS void* laD0 = (LDS_AS void*)(&ldsA[wid * 512]);
    LDS_AS void* laD1 = (LDS_AS void*)(&ldsA[2048 + wid * 512]);
    LDS_AS void* lbD0 = (LDS_AS void*)(&ldsB[wid * 512]);
    LDS_AS void* lbD1 = (LDS_AS void*)(&ldsB[2048 + wid * 512]);

    const bf16x8* pa = (const bf16x8*)&ldsA[(wr * 64 + l15) * 32 + l4 * 8];
    const bf16x8* pb = (const bf16x8*)&ldsB[(wc * 64 + l15) * 32 + l4 * 8];

    f32x4 acc[4][4];
    const f32x4 z = {0.f, 0.f, 0.f, 0.f};
#pragma unroll
    for (int i = 0; i < 4; i++)
#pragma unroll
        for (int j = 0; j < 4; j++) acc[i][j] = z;

    const int nk = K >> 5;
    for (int kt = 0; kt < nk; ++kt) {
        const unsigned short* ga = ga0 + kt * 32;
        const unsigned short* gb = gb0 + kt * 32;
        __builtin_amdgcn_global_load_lds((const GLB_AS void*)ga,         laD0, 16, 0, 0);
        __builtin_amdgcn_global_load_lds((const GLB_AS void*)(ga + a64), laD1, 16, 0, 0);
        __builtin_amdgcn_global_load_lds((const GLB_AS void*)gb,         lbD0, 16, 0, 0);
        __builtin_amdgcn_global_load_lds((const GLB_AS void*)(gb + b64), lbD1, 16, 0, 0);
        __syncthreads();

        bf16x8 af[4], bfr[4];
#pragma unroll
        for (int mi = 0; mi < 4; mi++) af[mi]  = pa[mi * 64];
#pragma unroll
        for (int ni = 0; ni < 4; ni++) bfr[ni] = pb[ni * 64];
#pragma unroll
        for (int mi = 0; mi < 4; mi++)
#pragma unroll
            for (int ni = 0; ni < 4; ni++)
                acc[mi][ni] = __builtin_amdgcn_mfma_f32_16x16x32_bf16(af[mi], bfr[ni], acc[mi][ni], 0, 0, 0);
        __syncthreads();
    }

    const int row0 = bm * 128 + wr * 64;
    const int col0 = bn * 128 + wc * 64;
#pragma unroll
    for (int mi = 0; mi < 4; mi++) {
#pragma unroll
        for (int ni = 0; ni < 4; ni++) {
            f32x4 c = acc[mi][ni];
            const int col = col0 + ni * 16 + l15;
            float bv = 0.f, dv = 0.f;
            if (EPI != 3) bv = bias[col];
            if (EPI == 2) dv = dtab[col >> 1];
#pragma unroll
            for (int r = 0; r < 4; r++) {
                const int row = row0 + mi * 16 + l4 * 4 + r;
                float v = c[r] + bv;
                if (EPI == 0) v = fmaxf(v, 0.f);
                if (EPI == 2) {
                    float ang = (float)row * dv;
                    v += (col & 1) ? cosf(ang) : sinf(ang);
                }
                if (EPI == 3) {
                    Cf[(size_t)row * ldc + col] = v * scale;
                } else {
                    Cb[(size_t)row * ldc + col] = f2bf(v);
                    if (EPI == 2) Cf[(size_t)row * ldc + col] = v;
                }
            }
        }
    }
}

// ---------------------------------------------------------------- v column (fp32)
__global__ __launch_bounds__(256) void vcol_kernel(const float* __restrict__ Hf,
                                                   const float* __restrict__ ipw,
                                                   const float* __restrict__ ipb,
                                                   float* __restrict__ v) {
    const int row = blockIdx.x * 4 + (threadIdx.x >> 6);
    const int lane = threadIdx.x & 63;
    const float* w = ipw + (size_t)1535 * 512;
    const float* h = Hf + (size_t)row * 512;
    float s = 0.f;
    for (int k = lane; k < 512; k += 64) s += h[k] * w[k];
#pragma unroll
    for (int off = 32; off; off >>= 1) s += __shfl_down(s, off);
    if (lane == 0) v[row] = s + ipb[1535];
}

// ---------------------------------------------------------------- attention rows 3584..4095
__global__ __launch_bounds__(256) void attn_rows(const float* __restrict__ S1,
                                                 const float* __restrict__ S2,
                                                 const float* __restrict__ v,
                                                 const float* __restrict__ lamp,
                                                 float* __restrict__ out) {
    const int r = blockIdx.x;
    const int tid = threadIdx.x, lane = tid & 63, wid = tid >> 6;
    const float* s1 = S1 + (size_t)r * 4096;
    const float* s2 = S2 + (size_t)r * 4096;
    __shared__ float red[4][8];

    float m1 = -1e30f, m2 = -1e30f;
    for (int i = tid; i < 4096; i += 256) {
        m1 = fmaxf(m1, s1[i]);
        m2 = fmaxf(m2, s2[i]);
    }
#pragma unroll
    for (int off = 32; off; off >>= 1) {
        m1 = fmaxf(m1, __shfl_down(m1, off));
        m2 = fmaxf(m2, __shfl_down(m2, off));
    }
    if (lane == 0) { red[wid][0] = m1; red[wid][1] = m2; }
    __syncthreads();
    m1 = fmaxf(fmaxf(red[0][0], red[1][0]), fmaxf(red[2][0], red[3][0]));
    m2 = fmaxf(fmaxf(red[0][1], red[1][1]), fmaxf(red[2][1], red[3][1]));

    const int gj = 3584 + r;
    float e1 = 0.f, e2 = 0.f, d1 = 0.f, d2 = 0.f, cs = 0.f;
    for (int i = tid; i < 4096; i += 256) {
        float p1 = expf(s1[i] - m1);
        float p2 = expf(s2[i] - m2);
        float vv = v[i];
        e1 += p1; e2 += p2; d1 += p1 * vv; d2 += p2 * vv;
        if (i > gj) cs += vv;
    }
#pragma unroll
    for (int off = 32; off; off >>= 1) {
        e1 += __shfl_down(e1, off); e2 += __shfl_down(e2, off);
        d1 += __shfl_down(d1, off); d2 += __shfl_down(d2, off);
        cs += __shfl_down(cs, off);
    }
    __syncthreads();
    if (lane == 0) {
        red[wid][0] = e1; red[wid][1] = e2; red[wid][2] = d1; red[wid][3] = d2; red[wid][4] = cs;
    }
    __syncthreads();
    if (tid == 0) {
        e1 = red[0][0] + red[1][0] + red[2][0] + red[3][0];
        e2 = red[0][1] + red[1][1] + red[2][1] + red[3][1];
        d1 = red[0][2] + red[1][2] + red[2][2] + red[3][2];
        d2 = red[0][3] + red[1][3] + red[2][3] + red[3][3];
        cs = red[0][4] + red[1][4] + red[2][4] + red[3][4];
        out[r] = d1 / e1 - lamp[0] * (d2 / e2) + cs;
    }
}

// ---------------------------------------------------------------- fp32 mat-vec, wave per output
template<int RELU>
__global__ __launch_bounds__(256) void matvec(const float* __restrict__ W, const float* __restrict__ x,
                                              const float* __restrict__ b, float* __restrict__ y,
                                              int N, int K) {
    const int o = blockIdx.x * 4 + (threadIdx.x >> 6);
    const int lane = threadIdx.x & 63;
    if (o >= N) return;
    const float* w = W + (size_t)o * K;
    float s = 0.f;
    for (int k = lane; k < K; k += 64) s += w[k] * x[k];
#pragma unroll
    for (int off = 32; off; off >>= 1) s += __shfl_down(s, off);
    if (lane == 0) y[o] = RELU ? fmaxf(s + b[o], 0.f) : (s + b[o]);
}

// ---------------------------------------------------------------- softmax over 256 logits
__global__ __launch_bounds__(256) void softmax256(const float* __restrict__ lg, float* __restrict__ out) {
    const int tid = threadIdx.x, lane = tid & 63, wid = tid >> 6;
    __shared__ float rm[4], rs[4];
    float l = lg[tid];
    float m = l;
#pragma unroll
    for (int off = 32; off; off >>= 1) m = fmaxf(m, __shfl_down(m, off));
    if (lane == 0) rm[wid] = m;
    __syncthreads();
    m = fmaxf(fmaxf(rm[0], rm[1]), fmaxf(rm[2], rm[3]));
    float e = expf(l - m);
    float s = e;
#pragma unroll
    for (int off = 32; off; off >>= 1) s += __shfl_down(s, off);
    if (lane == 0) rs[wid] = s;
    __syncthreads();
    s = rs[0] + rs[1] + rs[2] + rs[3];
    out[tid] = e / s;
}

// ---------------------------------------------------------------- launch
extern "C" void kernel_launch(void* const* d_in, const int* in_sizes, int n_in,
                              void* d_out, int out_size, void* d_ws, size_t ws_size,
                              hipStream_t stream) {
    const float* x      = (const float*)d_in[0];
    const float* enc_w1 = (const float*)d_in[1];
    const float* enc_b1 = (const float*)d_in[2];
    const float* enc_w2 = (const float*)d_in[3];
    const float* enc_b2 = (const float*)d_in[4];
    const float* enc_w3 = (const float*)d_in[5];
    const float* enc_b3 = (const float*)d_in[6];
    const float* enc_w4 = (const float*)d_in[7];
    const float* enc_b4 = (const float*)d_in[8];
    const float* ipw    = (const float*)d_in[9];
    const float* ipb    = (const float*)d_in[10];
    const float* opw    = (const float*)d_in[11];
    const float* opb    = (const float*)d_in[12];
    const float* lam    = (const float*)d_in[13];
    const float* aw1    = (const float*)d_in[14];
    const float* ab1    = (const float*)d_in[15];
    const float* aw2    = (const float*)d_in[16];
    const float* ab2    = (const float*)d_in[17];
    const float* aw3    = (const float*)d_in[18];
    const float* ab3    = (const float*)d_in[19];

    char* ws = (char*)d_ws;
    const size_t MB = 1ull << 20;
    unsigned short* bufA = (unsigned short*)(ws);             // 32MB: Xb then C2b
    unsigned short* bufB = (unsigned short*)(ws + 32 * MB);   // 16MB: C1b then C3b
    float* S1            = (float*)(ws + 32 * MB);            // 8MB (after C3b dead)
    float* S2            = (float*)(ws + 40 * MB);            // 8MB
    unsigned short* Wb   = (unsigned short*)(ws + 48 * MB);   // 16MB: per-layer weight bf16
    unsigned short* IPb  = (unsigned short*)(ws + 64 * MB);   // 1.5MB
    unsigned short* Hb   = (unsigned short*)(ws + 66 * MB);   // 4MB
    float* Hf            = (float*)(ws + 70 * MB);            // 8MB
    unsigned short* Kb   = (unsigned short*)(ws + 78 * MB);   // 4MB
    unsigned short* Qb   = (unsigned short*)(ws + 82 * MB);   // 0.5MB
    float* vcol          = (float*)(ws + 83 * MB);
    float* dtab          = (float*)(ws + 83 * MB + 64 * 1024);
    float* attnv         = (float*)(ws + 83 * MB + 128 * 1024);
    float* hh            = (float*)(ws + 83 * MB + 192 * 1024);
    float* h1            = (float*)(ws + 83 * MB + 256 * 1024);
    float* h2            = (float*)(ws + 83 * MB + 320 * 1024);
    float* lg            = (float*)(ws + 83 * MB + 384 * 1024);

    auto cvt = [&](const float* in, unsigned short* outp, int n) {
        int n4 = n >> 2;
        int blocks = (n4 + 255) / 256;
        if (blocks > 2048) blocks = 2048;
        cvt_f32_bf16<<<dim3(blocks), dim3(256), 0, stream>>>(in, outp, n4);
    };

    divtab_kernel<<<dim3(1), dim3(256), 0, stream>>>(dtab);

    // ---- encoder (big 3 on the 3-buffer BK=64 kernel, full grids) ----
    cvt(x, bufA, 4096 * 1024);
    cvt(enc_w1, Wb, 2048 * 1024);
    gemm8p<1><<<dim3(32 * 8), dim3(512), 0, stream>>>(bufA, 1024, Wb, 1024,
                                                      4096, 2048, 1024, enc_b1, bufB, 2048);
    cvt(enc_w2, Wb, 4096 * 2048);
    gemm8p<2><<<dim3(32 * 16), dim3(512), 0, stream>>>(bufB, 2048, Wb, 2048,
                                                       4096, 4096, 2048, enc_b2, bufA, 4096);
    cvt(enc_w3, Wb, 2048 * 4096);
    gemm8p<3><<<dim3(32 * 8), dim3(512), 0, stream>>>(bufA, 4096, Wb, 4096,
                                                      4096, 2048, 4096, enc_b3, bufB, 2048);
    cvt(enc_w4, Wb, 512 * 2048);
    gemm_bt<2><<<dim3(32 * 4), dim3(256), 0, stream>>>(bufB, 2048, Wb, 2048, 4096, 512, 2048,
                                                       enc_b4, Hb, Hf, 512, 1.f, dtab);

    // ---- projections (K full, Q only rows 3584.., v one column) ----
    cvt(ipw, IPb, 1536 * 512);
    gemm_bt<1><<<dim3(32 * 4), dim3(256), 0, stream>>>(Hb, 512, IPb + 512 * 512, 512, 4096, 512, 512,
                                                       ipb + 512, Kb, nullptr, 512, 1.f, nullptr);
    gemm_bt<1><<<dim3(4 * 4), dim3(256), 0, stream>>>(Hb + (size_t)3584 * 512, 512, IPb, 512, 512, 512, 512,
                                                      ipb, Qb, nullptr, 512, 1.f, nullptr);
    vcol_kernel<<<dim3(1024), dim3(256), 0, stream>>>(Hf, ipw, ipb, vcol);

    // ---- scores (512 x 4096, two heads) ----
    const float rs2 = 0.70710678118654752f;
    gemm_bt<3><<<dim3(4 * 32), dim3(256), 0, stream>>>(Qb, 512, Kb, 512, 512, 4096, 256,
                                                       nullptr, nullptr, S1, 4096, rs2, nullptr);
    gemm_bt<3><<<dim3(4 * 32), dim3(256), 0, stream>>>(Qb + 256, 512, Kb + 256, 512, 512, 4096, 256,
                                                       nullptr, nullptr, S2, 4096, rs2, nullptr);

    // ---- softmax + diff + causal + v-dot ----
    attn_rows<<<dim3(512), dim3(256), 0, stream>>>(S1, S2, vcol, lam, attnv);

    // ---- fp32 tail (single row) ----
    matvec<0><<<dim3(128), dim3(256), 0, stream>>>(opw, attnv, opb, hh, 512, 512);
    matvec<1><<<dim3(256), dim3(256), 0, stream>>>(aw1, hh, ab1, h1, 1024, 512);
    matvec<1><<<dim3(512), dim3(256), 0, stream>>>(aw2, h1, ab2, h2, 2048, 1024);
    matvec<0><<<dim3(64), dim3(256), 0, stream>>>(aw3, h2, ab3, lg, 256, 2048);
    softmax256<<<dim3(1), dim3(256), 0, stream>>>(lg, (float*)d_out);
}